// Round 12
// baseline (349.629 us; speedup 1.0000x reference)
//
#include <hip/hip_runtime.h>
#include <cstdint>

#define N_IMG 1024
#define D_DIM 512
#define C_CLS 100000
#define C_PAD 100096            // 782 * 128
#define NPAN 782                // 128-col B panels
#define SCALE_LN2 92.33248261689366f  // 64 / ln(2)
#define COS_M 0.8775825618903728f
#define SIN_M 0.479425538604203f

typedef __attribute__((ext_vector_type(4))) int int4v;

#define GLD16(g, l) __builtin_amdgcn_global_load_lds( \
    (const __attribute__((address_space(1))) void*)(g), \
    (__attribute__((address_space(3))) void*)(l), 16, 0, 0)

static __device__ __forceinline__ uint pk4(float a, float b, float c, float d,
                                           float qs) {
  int ia = (int)rintf(a * qs), ib = (int)rintf(b * qs);
  int ic = (int)rintf(c * qs), id = (int)rintf(d * qs);
  return (ia & 255) | ((ib & 255) << 8) | ((ic & 255) << 16) | ((id & 255) << 24);
}

static __device__ __forceinline__ int dp8(uint a, uint b) {
  int s = 0;
  #pragma unroll
  for (int i = 0; i < 4; ++i)
    s += (int)(signed char)((a >> (8 * i)) & 255) *
         (int)(signed char)((b >> (8 * i)) & 255);
  return s;
}

// DPP reduction step over 16-lane rows (VALU pipe — no LDS ops)
template <int CTRL>
static __device__ __forceinline__ float dpp_red(float s) {
  int t = __builtin_amdgcn_update_dpp(0, __builtin_bit_cast(int, s),
                                      CTRL, 0xF, 0xF, false);
  return s + __builtin_bit_cast(float, t);
}

// --------------------------- row L2-normalize + symmetric int8 quantization
// (r9-proven producer: one wave per row, row read once, contiguous 2 KB)
__global__ __launch_bounds__(256) void norm_q(
    const float* __restrict__ src, signed char* __restrict__ dst,
    float* __restrict__ scale, float* __restrict__ inv, int nvalid, int nrows)
{
  int row = blockIdx.x * 4 + (threadIdx.x >> 6);
  int lane = threadIdx.x & 63;
  if (row >= nrows) return;
  if (row >= nvalid) {                 // pad rows: zero q + zero scale
    uint2 z; z.x = 0u; z.y = 0u;
    ((uint2*)(dst + (size_t)row * D_DIM))[lane] = z;
    if (lane == 0) scale[row] = 0.f;
    return;
  }
  const float4* sp = (const float4*)(src + (size_t)row * D_DIM);
  float4 a = sp[2 * lane], b = sp[2 * lane + 1];   // 8 consecutive elements
  float ss = a.x*a.x + a.y*a.y + a.z*a.z + a.w*a.w
           + b.x*b.x + b.y*b.y + b.z*b.z + b.w*b.w;
  float am = fmaxf(fmaxf(fmaxf(fabsf(a.x), fabsf(a.y)),
                         fmaxf(fabsf(a.z), fabsf(a.w))),
                   fmaxf(fmaxf(fabsf(b.x), fabsf(b.y)),
                         fmaxf(fabsf(b.z), fabsf(b.w))));
  #pragma unroll
  for (int off = 1; off < 64; off <<= 1) {
    ss += __shfl_xor(ss, off);
    am = fmaxf(am, __shfl_xor(am, off));
  }
  am = fmaxf(am, 1e-30f);
  float iv = 1.0f / fmaxf(sqrtf(ss), 1e-12f);
  float qs = 127.0f / am;
  if (lane == 0) { inv[row] = iv; scale[row] = am * iv * (1.0f / 127.0f); }
  uint2 o;
  o.x = pk4(a.x, a.y, a.z, a.w, qs);
  o.y = pk4(b.x, b.y, b.z, b.w, qs);
  ((uint2*)(dst + (size_t)row * D_DIM))[lane] = o;
}

// --------------------- i8 GEMM: B panel resident in LDS, barrier-free K-loop
// One block per 128-col panel (782 blocks, 256 thr, 4 waves, 2 blocks/CU,
// LDS 68 KB). Stage pre-quantized panel once via global_load_lds (single
// vmcnt(0)+barrier), then ZERO barriers: per wave, 4 stripes of 64 rows,
// acc[4][8] (128 AGPR); per kt: 4 A-frags global->reg (L2-hot 512 KB),
// 8 B-frags ds_read from static LDS, 32 MFMA. Waves free-run: epilogue VALU
// of one wave overlaps MFMA of the others (the m114 mechanism, finally
// available because nothing is in lockstep). Epilogue: dequant+exp2+DPP
// reduce into red[], one dense 4 KB store per block.
__global__ __launch_bounds__(256, 2) void gemm_fused(
    const signed char* __restrict__ Bg,     // nw_q [C_PAD][512] i8
    const signed char* __restrict__ Aq,     // ne_q [1024][512] i8
    const float* __restrict__ sa_img, const float* __restrict__ sb_w,
    float* __restrict__ partials)
{
  __shared__ __align__(16) signed char Bq[128 * 512];   // 64 KB
  __shared__ float red[1024];                           // 4 KB

  const int tid  = threadIdx.x;
  const int lane = tid & 63;
  const int w    = tid >> 6;            // 0..3
  const int l15  = lane & 15;
  const int l4   = lane >> 4;
  const int bn   = blockIdx.x;

  // ---- stage panel: 16 rounds x 4 KB. LDS linear dest; source pre-swizzled
  // with the involution d ^= ((d>>9)&7)<<4  (row = d>>9, 16B-slot bits 4-6).
  {
    const signed char* src = Bg + (size_t)bn * (128 * 512);
    #pragma unroll
    for (int i = 0; i < 16; ++i) {
      const int dbase = i * 4096 + w * 1024;     // wave-uniform
      const int d = dbase + lane * 16;           // this lane's dest byte
      const int s = d ^ (((d >> 9) & 7) << 4);
      GLD16(src + s, &Bq[dbase]);
    }
  }
  asm volatile("s_waitcnt vmcnt(0)" ::: "memory");
  __syncthreads();                               // the ONLY barrier pre-store

  // epilogue constants (per lane: its 8 panel cols)
  float sb2[8], offc[8];
  #pragma unroll
  for (int n = 0; n < 8; ++n) {
    int gcol = bn * 128 + n * 16 + l15;
    sb2[n]  = sb_w[gcol] * SCALE_LN2;            // sb_w[pad] = 0
    offc[n] = (gcol < C_CLS) ? 0.f : -1e38f;
  }

  const char* Bb = (const char*)Bq;
  #pragma unroll 1
  for (int st = 0; st < 4; ++st) {               // 4 stripes of 64 rows
    int4v acc[4][8] = {};                        // 128 AGPRs
    const int row0 = w * 256 + st * 64;
    #pragma unroll
    for (int kt = 0; kt < 8; ++kt) {
      const int kof = kt * 64 + l4 * 16;
      int4v af[4];
      #pragma unroll
      for (int mf = 0; mf < 4; ++mf)
        af[mf] = *(const int4v*)(Aq +
                   (size_t)(row0 + mf * 16 + l15) * D_DIM + kof);
      #pragma unroll
      for (int n = 0; n < 8; ++n) {
        const int c = n * 16 + l15;
        const int byt = (c * 512 + kof) ^ ((c & 7) << 4);
        int4v bf = *(const int4v*)(Bb + byt);
        #pragma unroll
        for (int mf = 0; mf < 4; ++mf)
          acc[mf][n] = __builtin_amdgcn_mfma_i32_16x16x64_i8(
              af[mf], bf, acc[mf][n], 0, 0, 0);
      }
    }
    // stripe epilogue: dequant + exp2 + DPP reduce -> red[] (unique rows)
    // C/D layout (m89, dtype-independent): col = l15, row_in_frag = l4*4 + j
    #pragma unroll
    for (int mf = 0; mf < 4; ++mf) {
      #pragma unroll
      for (int j = 0; j < 4; ++j) {
        const int row = row0 + mf * 16 + l4 * 4 + j;
        const float sa = sa_img[row];
        float s = 0.f;
        #pragma unroll
        for (int n = 0; n < 8; ++n) {
          float x = (float)acc[mf][n][j] * sa;
          s += __builtin_amdgcn_exp2f(fmaf(x, sb2[n], offc[n]));
        }
        s = dpp_red<0xB1>(s);   // quad_perm xor1
        s = dpp_red<0x4E>(s);   // quad_perm xor2
        s = dpp_red<0x124>(s);  // row_ror:4
        s = dpp_red<0x128>(s);  // row_ror:8
        if (l15 == 0) red[row] = s;
      }
    }
  }
  __syncthreads();
  #pragma unroll
  for (int t = 0; t < 4; ++t)                    // one dense 4 KB store
    partials[(size_t)bn * 1024 + t * 256 + tid] = red[t * 256 + tid];
}

// ---------------------------------------------------------------- zero rows
__global__ void zero_rows(float* p) {
  p[blockIdx.x * 256 + threadIdx.x] = 0.f;
}

// ------------------- row_sums[r] += partials chunk sums (32 blocks, atomic)
__global__ __launch_bounds__(256) void reduce_partials(
    const float* __restrict__ partials, float* __restrict__ row_sums)
{
  const int c = blockIdx.x >> 2;                  // bn-chunk 0..7
  const int gid = (blockIdx.x & 3) * 256 + threadIdx.x;
  const int b0 = c * 98;
  const int b1 = (b0 + 98 < NPAN) ? b0 + 98 : NPAN;
  float s = 0.f;
  for (int bn = b0; bn < b1; ++bn)
    s += partials[(size_t)bn * 1024 + gid];
  atomicAdd(&row_sums[gid], s);
}

// ---------------------------------------- per-row margin fixup + row loss
// Subtracts the quantized target term BIT-EXACTLY: same i32 dot from the
// stored q-vectors + the identical float expression as the GEMM epilogue
// (x = cvt(id)*sa; exp2(fmaf(x, sb_w*S, 0))).
__global__ __launch_bounds__(256) void fix_loss(
    const float* __restrict__ images, const float* __restrict__ weight,
    const int* __restrict__ labels, const float* __restrict__ img_inv,
    const float* __restrict__ w_inv,
    const signed char* __restrict__ ne_q, const signed char* __restrict__ nw_q,
    const float* __restrict__ sa_img, const float* __restrict__ sb_w,
    const float* __restrict__ row_sums, float* __restrict__ loss_buf)
{
  int row = blockIdx.x * 4 + (threadIdx.x >> 6);
  int lane = threadIdx.x & 63;
  int lab = labels[row];
  const float4* ip = (const float4*)(images + (size_t)row * D_DIM);
  const float4* wp = (const float4*)(weight + (size_t)lab * D_DIM);
  float4 a = ip[lane],       b = wp[lane];
  float4 a2 = ip[lane + 64], b2 = wp[lane + 64];
  float dot = a.x*b.x + a.y*b.y + a.z*b.z + a.w*b.w
            + a2.x*b2.x + a2.y*b2.y + a2.z*b2.z + a2.w*b2.w;
  uint qa0 = ((const uint*)(ne_q + (size_t)row * D_DIM))[lane];
  uint qa1 = ((const uint*)(ne_q + (size_t)row * D_DIM))[64 + lane];
  uint qb0 = ((const uint*)(nw_q + (size_t)lab * D_DIM))[lane];
  uint qb1 = ((const uint*)(nw_q + (size_t)lab * D_DIM))[64 + lane];
  int id = dp8(qa0, qb0) + dp8(qa1, qb1);
  #pragma unroll
  for (int off = 1; off < 64; off <<= 1) {
    dot += __shfl_xor(dot, off);
    id  += __shfl_xor(id, off);
  }
  if (lane == 0) {
    // quantized target logit — identical expression to GEMM epilogue
    float x  = (float)id * sa_img[row];
    float eq = __builtin_amdgcn_exp2f(fmaf(x, sb_w[lab] * SCALE_LN2, 0.f));
    // f32-exact target cosine + ArcFace margin
    float t = dot * img_inv[row] * w_inv[lab];
    t = fminf(fmaxf(t, -1.f), 1.f);
    float tadj = t * COS_M - sqrtf(fmaxf(1.f - t * t, 0.f)) * SIN_M;
    float s = row_sums[row] - eq
            + __builtin_amdgcn_exp2f(tadj * SCALE_LN2);
    loss_buf[row] = logf(s) - 64.f * tadj;
  }
}

// ------------------------------------------------------------ final mean
__global__ void final_reduce(const float* __restrict__ loss_buf,
                             float* __restrict__ out)
{
  __shared__ float sh[16];
  int tid = threadIdx.x;
  float v = loss_buf[tid];
  #pragma unroll
  for (int off = 1; off < 64; off <<= 1) v += __shfl_xor(v, off);
  if ((tid & 63) == 0) sh[tid >> 6] = v;
  __syncthreads();
  if (tid < 16) {
    float w = sh[tid];
    #pragma unroll
    for (int off = 1; off < 16; off <<= 1) w += __shfl_xor(w, off);
    if (tid == 0) out[0] = w * (1.0f / 1024.0f);
  }
}

// ----------------------------------------------------------------- launch
extern "C" void kernel_launch(void* const* d_in, const int* in_sizes, int n_in,
                              void* d_out, int out_size, void* d_ws, size_t ws_size,
                              hipStream_t stream) {
  const float* images = (const float*)d_in[0];
  const int*   labels = (const int*)d_in[1];
  const float* weight = (const float*)d_in[2];
  float* out = (float*)d_out;
  char* ws = (char*)d_ws;

  // workspace layout (512B-aligned offsets)
  float*       row_sums = (float*)(ws + 0);          //  4 KB
  float*       loss_buf = (float*)(ws + 4096);       //  4 KB
  float*       img_inv  = (float*)(ws + 8192);       //  4 KB
  float*       sa_img   = (float*)(ws + 12288);      //  4 KB
  float*       w_inv    = (float*)(ws + 16384);      //  ~400 KB (C_PAD)
  float*       sb_w     = (float*)(ws + 417792);     //  ~400 KB (C_PAD)
  float*       partials = (float*)(ws + 819200);     //  ~3.2 MB [782][1024]
  signed char* ne_q     = (signed char*)(ws + 4022272);  // 512 KB [1024][512]
  signed char* nw_q     = (signed char*)(ws + 4546560);  // ~51 MB [C_PAD][512]

  norm_q<<<N_IMG / 4, 256, 0, stream>>>(images, ne_q, sa_img, img_inv,
                                        N_IMG, N_IMG);
  norm_q<<<C_PAD / 4, 256, 0, stream>>>(weight, nw_q, sb_w, w_inv,
                                        C_CLS, C_PAD);
  zero_rows<<<4, 256, 0, stream>>>(row_sums);
  gemm_fused<<<NPAN, 256, 0, stream>>>(nw_q, ne_q, sa_img, sb_w, partials);
  reduce_partials<<<32, 256, 0, stream>>>(partials, row_sums);
  fix_loss<<<N_IMG / 4, 256, 0, stream>>>(images, weight, labels, img_inv,
                                          w_inv, ne_q, nw_q, sa_img, sb_w,
                                          row_sums, loss_buf);
  final_reduce<<<1, 1024, 0, stream>>>(loss_buf, out);
}

// Round 13
// 162.702 us; speedup vs baseline: 2.1489x; 2.1489x over previous
//
#include <hip/hip_runtime.h>
#include <cstdint>

#define N_IMG 1024
#define D_DIM 512
#define C_CLS 100000
#define C_PAD 100096            // 782 * 128
#define NPAN 782                // 128-col B panels
#define SCALE_LN2 92.33248261689366f  // 64 / ln(2)
#define COS_M 0.8775825618903728f
#define SIN_M 0.479425538604203f

typedef __attribute__((ext_vector_type(4))) int int4v;

#define GLD16(g, l) __builtin_amdgcn_global_load_lds( \
    (const __attribute__((address_space(1))) void*)(g), \
    (__attribute__((address_space(3))) void*)(l), 16, 0, 0)

static __device__ __forceinline__ uint pk4(float a, float b, float c, float d,
                                           float qs) {
  int ia = (int)rintf(a * qs), ib = (int)rintf(b * qs);
  int ic = (int)rintf(c * qs), id = (int)rintf(d * qs);
  return (ia & 255) | ((ib & 255) << 8) | ((ic & 255) << 16) | ((id & 255) << 24);
}

static __device__ __forceinline__ int dp8(uint a, uint b) {
  int s = 0;
  #pragma unroll
  for (int i = 0; i < 4; ++i)
    s += (int)(signed char)((a >> (8 * i)) & 255) *
         (int)(signed char)((b >> (8 * i)) & 255);
  return s;
}

// DPP reduction step over 16-lane rows (VALU pipe — no LDS ops)
template <int CTRL>
static __device__ __forceinline__ float dpp_red(float s) {
  int t = __builtin_amdgcn_update_dpp(0, __builtin_bit_cast(int, s),
                                      CTRL, 0xF, 0xF, false);
  return s + __builtin_bit_cast(float, t);
}

// --------------------------- row L2-normalize + symmetric int8 quantization
__global__ __launch_bounds__(256) void norm_q(
    const float* __restrict__ src, signed char* __restrict__ dst,
    float* __restrict__ scale, float* __restrict__ inv, int nvalid, int nrows)
{
  int row = blockIdx.x * 4 + (threadIdx.x >> 6);
  int lane = threadIdx.x & 63;
  if (row >= nrows) return;
  if (row >= nvalid) {                 // pad rows: zero q + zero scale
    uint2 z; z.x = 0u; z.y = 0u;
    ((uint2*)(dst + (size_t)row * D_DIM))[lane] = z;
    if (lane == 0) scale[row] = 0.f;
    return;
  }
  const float4* sp = (const float4*)(src + (size_t)row * D_DIM);
  float4 a = sp[2 * lane], b = sp[2 * lane + 1];   // 8 consecutive elements
  float ss = a.x*a.x + a.y*a.y + a.z*a.z + a.w*a.w
           + b.x*b.x + b.y*b.y + b.z*b.z + b.w*b.w;
  float am = fmaxf(fmaxf(fmaxf(fabsf(a.x), fabsf(a.y)),
                         fmaxf(fabsf(a.z), fabsf(a.w))),
                   fmaxf(fmaxf(fabsf(b.x), fabsf(b.y)),
                         fmaxf(fabsf(b.z), fabsf(b.w))));
  #pragma unroll
  for (int off = 1; off < 64; off <<= 1) {
    ss += __shfl_xor(ss, off);
    am = fmaxf(am, __shfl_xor(am, off));
  }
  am = fmaxf(am, 1e-30f);
  float iv = 1.0f / fmaxf(sqrtf(ss), 1e-12f);
  float qs = 127.0f / am;
  if (lane == 0) { inv[row] = iv; scale[row] = am * iv * (1.0f / 127.0f); }
  uint2 o;
  o.x = pk4(a.x, a.y, a.z, a.w, qs);
  o.y = pk4(b.x, b.y, b.z, b.w, qs);
  ((uint2*)(dst + (size_t)row * D_DIM))[lane] = o;
}

// --------------------- i8 GEMM: B panel resident in LDS, barrier-free K-loop
// r12 + spill fix: kt loop at unroll 1 with manual 1-deep A prefetch (32
// VGPR in flight instead of 128 from the full unroll), sb2/offc moved out of
// the K-loop live range. acc[4][8] = 128 AGPR; live VGPR ~70 -> no spill.
__global__ __launch_bounds__(256, 2) void gemm_fused(
    const signed char* __restrict__ Bg,     // nw_q [C_PAD][512] i8
    const signed char* __restrict__ Aq,     // ne_q [1024][512] i8
    const float* __restrict__ sa_img, const float* __restrict__ sb_w,
    float* __restrict__ partials)
{
  __shared__ __align__(16) signed char Bq[128 * 512];   // 64 KB
  __shared__ float red[1024];                           // 4 KB

  const int tid  = threadIdx.x;
  const int lane = tid & 63;
  const int w    = tid >> 6;            // 0..3
  const int l15  = lane & 15;
  const int l4   = lane >> 4;
  const int bn   = blockIdx.x;

  // ---- stage panel: 16 rounds x 4 KB. LDS linear dest; source pre-swizzled
  // with the involution d ^= ((d>>9)&7)<<4  (row = d>>9, 16B-slot bits 4-6).
  {
    const signed char* src = Bg + (size_t)bn * (128 * 512);
    #pragma unroll
    for (int i = 0; i < 16; ++i) {
      const int dbase = i * 4096 + w * 1024;     // wave-uniform
      const int d = dbase + lane * 16;           // this lane's dest byte
      const int s = d ^ (((d >> 9) & 7) << 4);
      GLD16(src + s, &Bq[dbase]);
    }
  }
  asm volatile("s_waitcnt vmcnt(0)" ::: "memory");
  __syncthreads();                               // the ONLY barrier pre-store

  const char* Bb = (const char*)Bq;
  const int bswz = (l15 & 7) << 4;

  #pragma unroll 1
  for (int st = 0; st < 4; ++st) {               // 4 stripes of 64 rows
    int4v acc[4][8] = {};                        // 128 AGPRs
    const int row0 = w * 256 + st * 64;
    const signed char* arow = Aq + (size_t)(row0 + l15) * D_DIM + l4 * 16;

    int4v afc[4];
    #pragma unroll
    for (int mf = 0; mf < 4; ++mf)
      afc[mf] = *(const int4v*)(arow + mf * 16 * D_DIM);

    #pragma unroll 1
    for (int kt = 0; kt < 8; ++kt) {
      int4v afn[4];
      if (kt < 7) {                              // prefetch next kt early
        #pragma unroll
        for (int mf = 0; mf < 4; ++mf)
          afn[mf] = *(const int4v*)(arow + mf * 16 * D_DIM + (kt + 1) * 64);
      }
      #pragma unroll
      for (int n = 0; n < 8; ++n) {
        const int byt = (((n * 16 + l15) * 512) + kt * 64 + l4 * 16) ^ bswz;
        int4v bf = *(const int4v*)(Bb + byt);
        #pragma unroll
        for (int mf = 0; mf < 4; ++mf)
          acc[mf][n] = __builtin_amdgcn_mfma_i32_16x16x64_i8(
              afc[mf], bf, acc[mf][n], 0, 0, 0);
      }
      if (kt < 7) {
        #pragma unroll
        for (int mf = 0; mf < 4; ++mf) afc[mf] = afn[mf];
      }
    }

    // stripe epilogue: dequant + exp2 + DPP reduce -> red[] (unique rows)
    // C/D layout (m89, dtype-independent): col = l15, row_in_frag = l4*4 + j
    float sb2[8], offc[8];
    #pragma unroll
    for (int n = 0; n < 8; ++n) {
      int gcol = bn * 128 + n * 16 + l15;
      sb2[n]  = sb_w[gcol] * SCALE_LN2;          // sb_w[pad] = 0
      offc[n] = (gcol < C_CLS) ? 0.f : -1e38f;
    }
    #pragma unroll
    for (int mf = 0; mf < 4; ++mf) {
      #pragma unroll
      for (int j = 0; j < 4; ++j) {
        const int row = row0 + mf * 16 + l4 * 4 + j;
        const float sa = sa_img[row];
        float s = 0.f;
        #pragma unroll
        for (int n = 0; n < 8; ++n) {
          float x = (float)acc[mf][n][j] * sa;
          s += __builtin_amdgcn_exp2f(fmaf(x, sb2[n], offc[n]));
        }
        s = dpp_red<0xB1>(s);   // quad_perm xor1
        s = dpp_red<0x4E>(s);   // quad_perm xor2
        s = dpp_red<0x124>(s);  // row_ror:4
        s = dpp_red<0x128>(s);  // row_ror:8
        if (l15 == 0) red[row] = s;
      }
    }
  }
  __syncthreads();
  #pragma unroll
  for (int t = 0; t < 4; ++t)                    // one dense 4 KB store
    partials[(size_t)bn * 1024 + t * 256 + tid] = red[t * 256 + tid];
}

// ---------------------------------------------------------------- zero rows
__global__ void zero_rows(float* p) {
  p[blockIdx.x * 256 + threadIdx.x] = 0.f;
}

// ------------------- row_sums[r] += partials chunk sums (32 blocks, atomic)
__global__ __launch_bounds__(256) void reduce_partials(
    const float* __restrict__ partials, float* __restrict__ row_sums)
{
  const int c = blockIdx.x >> 2;                  // bn-chunk 0..7
  const int gid = (blockIdx.x & 3) * 256 + threadIdx.x;
  const int b0 = c * 98;
  const int b1 = (b0 + 98 < NPAN) ? b0 + 98 : NPAN;
  float s = 0.f;
  for (int bn = b0; bn < b1; ++bn)
    s += partials[(size_t)bn * 1024 + gid];
  atomicAdd(&row_sums[gid], s);
}

// ---------------------------------------- per-row margin fixup + row loss
// Subtracts the quantized target term BIT-EXACTLY: same i32 dot from the
// stored q-vectors + the identical float expression as the GEMM epilogue.
__global__ __launch_bounds__(256) void fix_loss(
    const float* __restrict__ images, const float* __restrict__ weight,
    const int* __restrict__ labels, const float* __restrict__ img_inv,
    const float* __restrict__ w_inv,
    const signed char* __restrict__ ne_q, const signed char* __restrict__ nw_q,
    const float* __restrict__ sa_img, const float* __restrict__ sb_w,
    const float* __restrict__ row_sums, float* __restrict__ loss_buf)
{
  int row = blockIdx.x * 4 + (threadIdx.x >> 6);
  int lane = threadIdx.x & 63;
  int lab = labels[row];
  const float4* ip = (const float4*)(images + (size_t)row * D_DIM);
  const float4* wp = (const float4*)(weight + (size_t)lab * D_DIM);
  float4 a = ip[lane],       b = wp[lane];
  float4 a2 = ip[lane + 64], b2 = wp[lane + 64];
  float dot = a.x*b.x + a.y*b.y + a.z*b.z + a.w*b.w
            + a2.x*b2.x + a2.y*b2.y + a2.z*b2.z + a2.w*b2.w;
  uint qa0 = ((const uint*)(ne_q + (size_t)row * D_DIM))[lane];
  uint qa1 = ((const uint*)(ne_q + (size_t)row * D_DIM))[64 + lane];
  uint qb0 = ((const uint*)(nw_q + (size_t)lab * D_DIM))[lane];
  uint qb1 = ((const uint*)(nw_q + (size_t)lab * D_DIM))[64 + lane];
  int id = dp8(qa0, qb0) + dp8(qa1, qb1);
  #pragma unroll
  for (int off = 1; off < 64; off <<= 1) {
    dot += __shfl_xor(dot, off);
    id  += __shfl_xor(id, off);
  }
  if (lane == 0) {
    // quantized target logit — identical expression to GEMM epilogue
    float x  = (float)id * sa_img[row];
    float eq = __builtin_amdgcn_exp2f(fmaf(x, sb_w[lab] * SCALE_LN2, 0.f));
    // f32-exact target cosine + ArcFace margin
    float t = dot * img_inv[row] * w_inv[lab];
    t = fminf(fmaxf(t, -1.f), 1.f);
    float tadj = t * COS_M - sqrtf(fmaxf(1.f - t * t, 0.f)) * SIN_M;
    float s = row_sums[row] - eq
            + __builtin_amdgcn_exp2f(tadj * SCALE_LN2);
    loss_buf[row] = logf(s) - 64.f * tadj;
  }
}

// ------------------------------------------------------------ final mean
__global__ void final_reduce(const float* __restrict__ loss_buf,
                             float* __restrict__ out)
{
  __shared__ float sh[16];
  int tid = threadIdx.x;
  float v = loss_buf[tid];
  #pragma unroll
  for (int off = 1; off < 64; off <<= 1) v += __shfl_xor(v, off);
  if ((tid & 63) == 0) sh[tid >> 6] = v;
  __syncthreads();
  if (tid < 16) {
    float w = sh[tid];
    #pragma unroll
    for (int off = 1; off < 16; off <<= 1) w += __shfl_xor(w, off);
    if (tid == 0) out[0] = w * (1.0f / 1024.0f);
  }
}

// ----------------------------------------------------------------- launch
extern "C" void kernel_launch(void* const* d_in, const int* in_sizes, int n_in,
                              void* d_out, int out_size, void* d_ws, size_t ws_size,
                              hipStream_t stream) {
  const float* images = (const float*)d_in[0];
  const int*   labels = (const int*)d_in[1];
  const float* weight = (const float*)d_in[2];
  float* out = (float*)d_out;
  char* ws = (char*)d_ws;

  // workspace layout (512B-aligned offsets)
  float*       row_sums = (float*)(ws + 0);          //  4 KB
  float*       loss_buf = (float*)(ws + 4096);       //  4 KB
  float*       img_inv  = (float*)(ws + 8192);       //  4 KB
  float*       sa_img   = (float*)(ws + 12288);      //  4 KB
  float*       w_inv    = (float*)(ws + 16384);      //  ~400 KB (C_PAD)
  float*       sb_w     = (float*)(ws + 417792);     //  ~400 KB (C_PAD)
  float*       partials = (float*)(ws + 819200);     //  ~3.2 MB [782][1024]
  signed char* ne_q     = (signed char*)(ws + 4022272);  // 512 KB [1024][512]
  signed char* nw_q     = (signed char*)(ws + 4546560);  // ~51 MB [C_PAD][512]

  norm_q<<<N_IMG / 4, 256, 0, stream>>>(images, ne_q, sa_img, img_inv,
                                        N_IMG, N_IMG);
  norm_q<<<C_PAD / 4, 256, 0, stream>>>(weight, nw_q, sb_w, w_inv,
                                        C_CLS, C_PAD);
  zero_rows<<<4, 256, 0, stream>>>(row_sums);
  gemm_fused<<<NPAN, 256, 0, stream>>>(nw_q, ne_q, sa_img, sb_w, partials);
  reduce_partials<<<32, 256, 0, stream>>>(partials, row_sums);
  fix_loss<<<N_IMG / 4, 256, 0, stream>>>(images, weight, labels, img_inv,
                                          w_inv, ne_q, nw_q, sa_img, sb_w,
                                          row_sums, loss_buf);
  final_reduce<<<1, 1024, 0, stream>>>(loss_buf, out);
}